// Round 10
// baseline (10043.457 us; speedup 1.0000x reference)
//
#include <hip/hip_runtime.h>
#include <hip/hip_bf16.h>
#include <math.h>

#define B 2048
#define NN 30
#define H 256
#define EDIM 256
#define G4 1024  // 4*H
#define NBLK 512 // persistent grid: 512 blocks x 512 thr = 2 blocks/CU, all resident

__device__ __forceinline__ float fsig(float x) {
    return __fdividef(1.f, 1.f + __expf(-x));
}
__device__ __forceinline__ float ftanh(float x) {
    return 1.f - __fdividef(2.f, __expf(2.f * x) + 1.f);
}

// ---------------------------------------------------------------------------
// Big precompute GEMM (R7-proven: 294us, FETCH 37MB)
// ---------------------------------------------------------------------------
__global__ __launch_bounds__(256)
void gemm_big(const float* __restrict__ A,
              const float* __restrict__ W0, const float* __restrict__ W1,
              const float* __restrict__ W2,
              const float* __restrict__ b0, const float* __restrict__ b1,
              const float* __restrict__ b2,
              float* __restrict__ C0, float* __restrict__ C1,
              float* __restrict__ C2)
{
    __shared__ __align__(16) float As[16][128];
    __shared__ __align__(16) float Ws[16][128];
    int tid = threadIdx.x;
    int tx = tid & 15, ty = (tid >> 4) & 15;

    int lin = blockIdx.y * 6 + blockIdx.x;
    int v = (lin & 7) * 360 + (lin >> 3);
    int m0 = (v / 6) << 7;
    int nblk = v % 6;
    int part = nblk >> 1;
    int nin = (nblk & 1) << 7;
    const float* W    = part == 0 ? W0 : part == 1 ? W1 : W2;
    const float* bias = part == 0 ? b0 : part == 1 ? b1 : b2;
    float* C          = part == 0 ? C0 : part == 1 ? C1 : C2;

    int lr = tid >> 1;
    int lk8 = (tid & 1) << 3;
    const float* arow = A + (long)(m0 + lr) * 256 + lk8;
    const float* wrow = W + (long)(nin + lr) * 256 + lk8;
    float4 a0 = *(const float4*)(arow);
    float4 a1 = *(const float4*)(arow + 4);
    float4 w0 = *(const float4*)(wrow);
    float4 w1 = *(const float4*)(wrow + 4);
    float acc[8][8] = {};

    for (int k0 = 0; k0 < 256; k0 += 16) {
        As[lk8 + 0][lr] = a0.x; As[lk8 + 1][lr] = a0.y;
        As[lk8 + 2][lr] = a0.z; As[lk8 + 3][lr] = a0.w;
        As[lk8 + 4][lr] = a1.x; As[lk8 + 5][lr] = a1.y;
        As[lk8 + 6][lr] = a1.z; As[lk8 + 7][lr] = a1.w;
        Ws[lk8 + 0][lr] = w0.x; Ws[lk8 + 1][lr] = w0.y;
        Ws[lk8 + 2][lr] = w0.z; Ws[lk8 + 3][lr] = w0.w;
        Ws[lk8 + 4][lr] = w1.x; Ws[lk8 + 5][lr] = w1.y;
        Ws[lk8 + 6][lr] = w1.z; Ws[lk8 + 7][lr] = w1.w;
        __syncthreads();
        if (k0 + 16 < 256) {
            a0 = *(const float4*)(arow + k0 + 16);
            a1 = *(const float4*)(arow + k0 + 20);
            w0 = *(const float4*)(wrow + k0 + 16);
            w1 = *(const float4*)(wrow + k0 + 20);
        }
        #pragma unroll
        for (int k = 0; k < 16; ++k) {
            float4 af0 = *(const float4*)&As[k][ty << 2];
            float4 af1 = *(const float4*)&As[k][64 + (ty << 2)];
            float4 wf0 = *(const float4*)&Ws[k][tx << 2];
            float4 wf1 = *(const float4*)&Ws[k][64 + (tx << 2)];
            float av[8] = {af0.x, af0.y, af0.z, af0.w, af1.x, af1.y, af1.z, af1.w};
            float wv[8] = {wf0.x, wf0.y, wf0.z, wf0.w, wf1.x, wf1.y, wf1.z, wf1.w};
            #pragma unroll
            for (int i = 0; i < 8; ++i)
                #pragma unroll
                for (int j = 0; j < 8; ++j)
                    acc[i][j] = fmaf(av[i], wv[j], acc[i][j]);
        }
        __syncthreads();
    }

    float bj[8];
    #pragma unroll
    for (int j = 0; j < 8; ++j) {
        int cj = nin + ((j < 4) ? (tx << 2) + j : 64 + (tx << 2) + j - 4);
        bj[j] = bias[cj];
    }
    #pragma unroll
    for (int i = 0; i < 8; ++i) {
        int m = m0 + ((i < 4) ? (ty << 2) + i : 64 + (ty << 2) + i - 4);
        float* crow = C + (long)m * 256 + nin;
        float4 v0 = make_float4(acc[i][0] + bj[0], acc[i][1] + bj[1],
                                acc[i][2] + bj[2], acc[i][3] + bj[3]);
        float4 v1 = make_float4(acc[i][4] + bj[4], acc[i][5] + bj[5],
                                acc[i][6] + bj[6], acc[i][7] + bj[7]);
        *(float4*)&crow[(tx << 2)] = v0;
        *(float4*)&crow[64 + (tx << 2)] = v1;
    }
}

__global__ void init_state(const unsigned char* __restrict__ vr, const int* __restrict__ start,
                           unsigned char* __restrict__ mask, unsigned char* __restrict__ knn,
                           int* __restrict__ idxs, unsigned* __restrict__ bar)
{
    int t = blockIdx.x * 256 + threadIdx.x;
    if (t < B * NN) { mask[t] = vr[t] ? 1 : 0; knn[t] = 0; }
    if (t < B) idxs[t] = start[t];
    if (t == 0) { bar[0] = 0u; bar[1] = 0u; }
}

// --------------------------- one-time prep kernels -------------------------
__global__ void prep_reorder(const float* __restrict__ Wih, const float* __restrict__ Whh,
                             const float* __restrict__ bih, const float* __restrict__ bhh,
                             float* __restrict__ Wih2, float* __restrict__ Whh2,
                             float* __restrict__ bg)
{
    int n = blockIdx.x, k = threadIdx.x;
    int src = ((n & 3) << 8) + (n >> 2);
    Wih2[(long)n * H + k] = Wih[(long)src * H + k];
    Whh2[(long)n * H + k] = Whh[(long)src * H + k];
    if (k == 0) bg[n] = bih[src] + bhh[src];
}

__global__ void prep_compose1(const float* __restrict__ Wqg, const float* __restrict__ Wm,
                              float* __restrict__ W1c)
{
    int h = blockIdx.x, k = threadIdx.x;
    float a = 0.f;
    for (int j = 0; j < H; ++j) a = fmaf(Wqg[(long)h * H + j], Wm[(long)j * 288 + k], a);
    W1c[(long)h * H + k] = a;
}

__global__ void prep_compose2(const float* __restrict__ Wqg, const float* __restrict__ Wm,
                              const float* __restrict__ bm, const float* __restrict__ bqg,
                              float* __restrict__ W2c, float* __restrict__ bc)
{
    int h = blockIdx.x, w = threadIdx.x;
    if (w < 32) {
        float a = 0.f;
        for (int j = 0; j < H; ++j) a = fmaf(Wqg[(long)h * H + j], Wm[(long)j * 288 + 256 + w], a);
        W2c[h * 32 + w] = a;
    } else if (w == 32) {
        float a = 0.f;
        for (int j = 0; j < H; ++j) a = fmaf(Wqg[(long)h * H + j], bm[j], a);
        bc[h] = a + bqg[h];
    }
}

__global__ __launch_bounds__(256)
void prep_qc(const float* __restrict__ cou, const float* __restrict__ W2c,
             const float* __restrict__ bc, float* __restrict__ qc)
{
    __shared__ float sWT[32 * 256];
    __shared__ float sb[256];
    int b = blockIdx.x, h = threadIdx.x;
    for (int i = h; i < 32 * 256; i += 256) {
        int hh = i >> 5, ww = i & 31;
        sWT[ww * 256 + hh] = W2c[i];
    }
    sb[h] = bc[h];
    __syncthreads();
    const float* cr = cou + (long)b * 32;
    float a = sb[h];
    for (int w = 0; w < 32; ++w) a = fmaf(cr[w], sWT[w * 256 + h], a);
    qc[(long)b * H + h] = a;
}

__global__ void prep_composeF(const float* __restrict__ Wqp, const float* __restrict__ Wrg,
                              const float* __restrict__ brg, float* __restrict__ WFc,
                              float* __restrict__ bFc)
{
    int f = blockIdx.x, k = threadIdx.x;
    float a = 0.f;
    for (int j = 0; j < H; ++j) a = fmaf(Wqp[(long)f * H + j], Wrg[(long)j * H + k], a);
    WFc[(long)f * H + k] = a;
    if (k == 0) {
        float s = 0.f;
        for (int j = 0; j < H; ++j) s = fmaf(Wqp[(long)f * H + j], brg[j], s);
        bFc[f] = s;
    }
}

// ---------------------------------------------------------------------------
// Persistent 30-step decode loop. 512 blocks x 512 threads, 2 blocks/CU
// guaranteed resident (VGPR<=128 via launch_bounds, LDS 51.5KB/block).
// Grid barrier: device-scope atomics + __threadfence (Guideline 16).
// Phase bodies are R7's proven kernels, math order identical.
// ---------------------------------------------------------------------------
__device__ __forceinline__ void grid_barrier(unsigned* cnt, unsigned* gen)
{
    __syncthreads();
    if (threadIdx.x == 0) {
        unsigned g0 = __hip_atomic_load(gen, __ATOMIC_RELAXED, __HIP_MEMORY_SCOPE_AGENT);
        __threadfence();   // release this block's data (writeback L2)
        unsigned prev = __hip_atomic_fetch_add(cnt, 1u, __ATOMIC_RELAXED,
                                               __HIP_MEMORY_SCOPE_AGENT);
        if (prev == NBLK - 1) {
            __hip_atomic_store(cnt, 0u, __ATOMIC_RELAXED, __HIP_MEMORY_SCOPE_AGENT);
            __threadfence();  // order reset before gen bump
            __hip_atomic_fetch_add(gen, 1u, __ATOMIC_RELAXED, __HIP_MEMORY_SCOPE_AGENT);
        } else {
            while (__hip_atomic_load(gen, __ATOMIC_RELAXED, __HIP_MEMORY_SCOPE_AGENT) == g0)
                __builtin_amdgcn_s_sleep(1);
        }
        __threadfence();   // acquire: invalidate stale L1/L2 lines
    }
    __syncthreads();
}

__global__ __launch_bounds__(512, 4)
void decode_loop(const float* __restrict__ decoder_input,
                 const float* __restrict__ emb,
                 const float* __restrict__ h0, const float* __restrict__ c0,
                 const float* __restrict__ Wih2, const float* __restrict__ Whh2,
                 const float* __restrict__ bg,
                 const float* __restrict__ W1c, const float* __restrict__ qc,
                 const float* __restrict__ eg, const float* __restrict__ ep,
                 const float* __restrict__ F,
                 const float* __restrict__ vg, const float* __restrict__ vp,
                 const float* __restrict__ bqp,
                 const float* __restrict__ D, const int* __restrict__ kminp,
                 unsigned char* __restrict__ mask, unsigned char* __restrict__ knn,
                 float* __restrict__ out, int* __restrict__ idxs,
                 float* __restrict__ hb0, float* __restrict__ hb1,
                 float* __restrict__ cb0, float* __restrict__ cb1,
                 float* __restrict__ qbuf, float* __restrict__ decb,
                 unsigned* __restrict__ bar)
{
    // gates LDS: [half][buf][k][m/n]
    __shared__ __align__(16) float gAs[2][2][16][68];
    __shared__ __align__(16) float gWs[2][2][16][68];
    // qg LDS
    __shared__ __align__(16) float qAs[2][16][36];
    __shared__ __align__(16) float qWs[2][16][68];
    // mega LDS
    __shared__ float sU[32], sP[32];
    __shared__ float sQp[H];
    __shared__ float sPar[2][H];
    __shared__ unsigned char sFull[32];
    __shared__ int sSel;

    int blk = blockIdx.x;
    int tid = threadIdx.x;
    unsigned* cnt = bar;
    unsigned* gen = bar + 1;

    const float* dec = decoder_input;
    const float* hin = h0;
    const float* cin = c0;

    for (int step = 0; step < NN; ++step) {
        float* hout = (step & 1) ? hb1 : hb0;
        float* cout = (step & 1) ? cb1 : cb0;

        // ================= GATES phase (blocks 0-255, two 256-thr halves) ====
        if (blk < 256) {
            int half = tid >> 8;
            int utid = tid & 255;
            int tx = utid & 15, ty = utid >> 4;
            int lin = (blk << 1) | half;           // 0..511 tile jobs
            int v = (lin & 7) * 64 + (lin >> 3);
            int m0 = (v >> 4) << 6;
            int n0 = (v & 15) << 6;

            int lr = utid >> 2;
            int lk = (utid & 3) << 2;
            const float* arow0 = dec + (long)(m0 + lr) * H;
            const float* arow1 = hin + (long)(m0 + lr) * H;
            const float* wrow0 = Wih2 + (long)(n0 + lr) * H;
            const float* wrow1 = Whh2 + (long)(n0 + lr) * H;

            float (*As)[16][68] = gAs[half];
            float (*Ws)[16][68] = gWs[half];

            float4 av = *(const float4*)(arow0 + lk);
            float4 wv = *(const float4*)(wrow0 + lk);
            As[0][lk + 0][lr] = av.x; As[0][lk + 1][lr] = av.y;
            As[0][lk + 2][lr] = av.z; As[0][lk + 3][lr] = av.w;
            Ws[0][lk + 0][lr] = wv.x; Ws[0][lk + 1][lr] = wv.y;
            Ws[0][lk + 2][lr] = wv.z; Ws[0][lk + 3][lr] = wv.w;
            __syncthreads();

            float acc[4][4] = {};
            int p = 0;
            for (int kk = 0; kk < 32; ++kk) {
                float4 nav, nwv;
                bool more = kk < 31;
                if (more) {
                    int nk = kk + 1;
                    const float* ar = (nk & 16) ? arow1 : arow0;
                    const float* wr = (nk & 16) ? wrow1 : wrow0;
                    int off = (nk & 15) << 4;
                    nav = *(const float4*)(ar + off + lk);
                    nwv = *(const float4*)(wr + off + lk);
                }
                #pragma unroll
                for (int k = 0; k < 16; ++k) {
                    float4 a4 = *(const float4*)&As[p][k][ty << 2];
                    float4 b4 = *(const float4*)&Ws[p][k][tx << 2];
                    float a[4] = {a4.x, a4.y, a4.z, a4.w};
                    float w[4] = {b4.x, b4.y, b4.z, b4.w};
                    #pragma unroll
                    for (int i = 0; i < 4; ++i)
                        #pragma unroll
                        for (int j = 0; j < 4; ++j)
                            acc[i][j] = fmaf(a[i], w[j], acc[i][j]);
                }
                if (more) {
                    int q = p ^ 1;
                    As[q][lk + 0][lr] = nav.x; As[q][lk + 1][lr] = nav.y;
                    As[q][lk + 2][lr] = nav.z; As[q][lk + 3][lr] = nav.w;
                    Ws[q][lk + 0][lr] = nwv.x; Ws[q][lk + 1][lr] = nwv.y;
                    Ws[q][lk + 2][lr] = nwv.z; Ws[q][lk + 3][lr] = nwv.w;
                }
                __syncthreads();
                p ^= 1;
            }

            int nb = n0 + (tx << 2);
            float b0 = bg[nb + 0], b1 = bg[nb + 1], b2 = bg[nb + 2], b3 = bg[nb + 3];
            int hq = (n0 >> 2) + tx;
            #pragma unroll
            for (int i = 0; i < 4; ++i) {
                int m = m0 + (ty << 2) + i;
                float gi_ = acc[i][0] + b0;
                float gf_ = acc[i][1] + b1;
                float gg_ = acc[i][2] + b2;
                float go_ = acc[i][3] + b3;
                float cv = cin[(long)m * H + hq];
                float cn = fsig(gf_) * cv + fsig(gi_) * ftanh(gg_);
                cout[(long)m * H + hq] = cn;
                hout[(long)m * H + hq] = fsig(go_) * ftanh(cn);
            }
        }
        grid_barrier(cnt, gen);

        // ================= QG phase (blocks 0-255, half 0 works) =============
        if (blk < 256) {
            int half = tid >> 8;
            int utid = tid & 255;
            int tx = utid & 15, ty = utid >> 4;
            int v = (blk & 7) * 32 + (blk >> 3);
            int m0 = (v >> 2) << 5;
            int n0 = (v & 3) << 6;

            int lrA = utid >> 3, lkA = (utid & 7) << 1;
            int lrW = utid >> 2, lkW = (utid & 3) << 2;
            const float* arow = hout + (long)(m0 + lrA) * 256;
            const float* wrow = W1c + (long)(n0 + lrW) * 256;

            if (!half) {
                float2 av = *(const float2*)(arow + lkA);
                float4 wv = *(const float4*)(wrow + lkW);
                qAs[0][lkA + 0][lrA] = av.x; qAs[0][lkA + 1][lrA] = av.y;
                qWs[0][lkW + 0][lrW] = wv.x; qWs[0][lkW + 1][lrW] = wv.y;
                qWs[0][lkW + 2][lrW] = wv.z; qWs[0][lkW + 3][lrW] = wv.w;
            }
            __syncthreads();

            float acc[2][4] = {};
            int p = 0;
            for (int k0 = 0; k0 < 256; k0 += 16) {
                bool more = (k0 + 16) < 256;
                if (!half) {
                    float2 nav; float4 nwv;
                    if (more) {
                        nav = *(const float2*)(arow + k0 + 16 + lkA);
                        nwv = *(const float4*)(wrow + k0 + 16 + lkW);
                    }
                    #pragma unroll
                    for (int k = 0; k < 16; ++k) {
                        float2 a2 = *(const float2*)&qAs[p][k][ty << 1];
                        float4 b4 = *(const float4*)&qWs[p][k][tx << 2];
                        acc[0][0] = fmaf(a2.x, b4.x, acc[0][0]);
                        acc[0][1] = fmaf(a2.x, b4.y, acc[0][1]);
                        acc[0][2] = fmaf(a2.x, b4.z, acc[0][2]);
                        acc[0][3] = fmaf(a2.x, b4.w, acc[0][3]);
                        acc[1][0] = fmaf(a2.y, b4.x, acc[1][0]);
                        acc[1][1] = fmaf(a2.y, b4.y, acc[1][1]);
                        acc[1][2] = fmaf(a2.y, b4.z, acc[1][2]);
                        acc[1][3] = fmaf(a2.y, b4.w, acc[1][3]);
                    }
                    if (more) {
                        int q = p ^ 1;
                        qAs[q][lkA + 0][lrA] = nav.x; qAs[q][lkA + 1][lrA] = nav.y;
                        qWs[q][lkW + 0][lrW] = nwv.x; qWs[q][lkW + 1][lrW] = nwv.y;
                        qWs[q][lkW + 2][lrW] = nwv.z; qWs[q][lkW + 3][lrW] = nwv.w;
                    }
                }
                __syncthreads();
                p ^= 1;
            }

            if (!half) {
                #pragma unroll
                for (int i = 0; i < 2; ++i) {
                    int m = m0 + (ty << 1) + i;
                    float4 adv = *(const float4*)&qc[(long)m * 256 + n0 + (tx << 2)];
                    float4 o = make_float4(acc[i][0] + adv.x, acc[i][1] + adv.y,
                                           acc[i][2] + adv.z, acc[i][3] + adv.w);
                    *(float4*)&qbuf[(long)m * 256 + n0 + (tx << 2)] = o;
                }
            }
        }
        grid_barrier(cnt, gen);

        // ================= MEGA phase (all blocks, 4 rows each) ==============
        {
            int wv = tid >> 6, lane = tid & 63;
            float4 vg4 = ((const float4*)vg)[lane];
            float4 vp4 = ((const float4*)vp)[lane];

            for (int rb = 0; rb < B / NBLK; ++rb) {
                int b = blk + rb * NBLK;
                float4 q4 = ((const float4*)(qbuf + (long)b * H))[lane];

                if (tid < 64) {
                    bool in = lane < NN;
                    int idx = idxs[b];
                    int kmin = *kminp;
                    unsigned char m = in ? mask[b * NN + lane] : (unsigned char)1;
                    float dv = in ? D[((long)b * NN + idx) * NN + lane] : 0.f;
                    unsigned long long unm = __ballot(in && !m);
                    int cnt2 = __popcll(unm);
                    bool valid = cnt2 > kmin;
                    float bw = (in && !m) ? dv : (in ? 0.f : -1.f);
                    int bi = in ? lane : 1000;
                    #pragma unroll
                    for (int off = 32; off; off >>= 1) {
                        float ow = __shfl_down(bw, off, 64);
                        int oi = __shfl_down(bi, off, 64);
                        if (ow > bw || (ow == bw && oi < bi)) { bw = ow; bi = oi; }
                    }
                    int far = __shfl(bi, 0, 64);
                    unsigned char mnew = (in && lane == idx) ? 1 : m;
                    #pragma unroll
                    for (int rep = 0; rep < 2; ++rep) {
                        bool allm = (__ballot(in && !mnew) == 0ull);
                        if (allm && lane == NN - 1) mnew = 0;
                    }
                    unsigned char kn = in ? knn[b * NN + lane] : 0;
                    if (in) {
                        sFull[lane] = (mnew | kn) ? 1 : 0;
                        mask[b * NN + lane] = mnew;
                        knn[b * NN + lane] = (lane == far && valid) ? 1 : 0;
                    }
                }
                __syncthreads();

                for (int n = wv; n < NN; n += 8) {
                    float4 e4 = ((const float4*)(eg + ((long)n * B + b) * H))[lane];
                    float s = vg4.x * ftanh(q4.x + e4.x);
                    s = fmaf(vg4.y, ftanh(q4.y + e4.y), s);
                    s = fmaf(vg4.z, ftanh(q4.z + e4.z), s);
                    s = fmaf(vg4.w, ftanh(q4.w + e4.w), s);
                    #pragma unroll
                    for (int off = 32; off; off >>= 1) s += __shfl_down(s, off, 64);
                    if (lane == 0) sU[n] = s;
                }
                __syncthreads();

                if (tid < 64) {
                    bool in = tid < NN;
                    bool f = in ? (sFull[tid] != 0) : true;
                    float u = (in && !f) ? sU[tid] : -INFINITY;
                    float mx = u;
                    #pragma unroll
                    for (int off = 32; off; off >>= 1) mx = fmaxf(mx, __shfl_down(mx, off, 64));
                    mx = __shfl(mx, 0, 64);
                    float p = (in && !f) ? __expf(u - mx) : 0.f;
                    float sum = p;
                    #pragma unroll
                    for (int off = 32; off; off >>= 1) sum += __shfl_down(sum, off, 64);
                    sum = __shfl(sum, 0, 64);
                    if (in) sP[tid] = p / sum;
                }
                __syncthreads();

                {
                    int half = tid >> 8, hh = tid & 255;
                    float a = 0.f;
                    #pragma unroll
                    for (int n = 0; n < 15; ++n) {
                        int nn = half * 15 + n;
                        a = fmaf(sP[nn], F[((long)nn * B + b) * H + hh], a);
                    }
                    sPar[half][hh] = a;
                }
                __syncthreads();
                if (tid < 256) sQp[tid] = bqp[tid] + sPar[0][tid] + sPar[1][tid];
                __syncthreads();

                float4 qp4 = ((const float4*)sQp)[lane];
                for (int n = wv; n < NN; n += 8) {
                    float4 e4 = ((const float4*)(ep + ((long)n * B + b) * H))[lane];
                    float s = vp4.x * ftanh(qp4.x + e4.x);
                    s = fmaf(vp4.y, ftanh(qp4.y + e4.y), s);
                    s = fmaf(vp4.z, ftanh(qp4.z + e4.z), s);
                    s = fmaf(vp4.w, ftanh(qp4.w + e4.w), s);
                    #pragma unroll
                    for (int off = 32; off; off >>= 1) s += __shfl_down(s, off, 64);
                    if (lane == 0) sU[n] = 10.f * ftanh(s);
                }
                __syncthreads();

                if (tid < 64) {
                    bool in = tid < NN;
                    bool f = in ? (sFull[tid] != 0) : true;
                    float l = (in && !f) ? sU[tid] : -INFINITY;
                    float mx = l; int bi = in ? tid : 1000;
                    #pragma unroll
                    for (int off = 32; off; off >>= 1) {
                        float om = __shfl_down(mx, off, 64);
                        int oi = __shfl_down(bi, off, 64);
                        if (om > mx || (om == mx && oi < bi)) { mx = om; bi = oi; }
                    }
                    mx = __shfl(mx, 0, 64);
                    bi = __shfl(bi, 0, 64);
                    float pe = (in && !f) ? __expf(l - mx) : 0.f;
                    float sum = pe;
                    #pragma unroll
                    for (int off = 32; off; off >>= 1) sum += __shfl_down(sum, off, 64);
                    sum = __shfl(sum, 0, 64);
                    float lse = mx + __logf(sum);
                    if (tid == 0) {
                        idxs[b] = bi;
                        out[(long)B * NN * NN + (long)b * NN + step] = (float)bi;
                        sSel = bi;
                    }
                    if (in)
                        out[(long)b * NN * NN + (long)step * NN + tid] =
                            f ? -1e30f : (l - lse);
                }
                __syncthreads();

                if (tid < 256) {
                    int sel = sSel;
                    decb[(long)b * H + tid] = emb[((long)sel * B + b) * EDIM + tid];
                }
                __syncthreads();
            }
        }
        grid_barrier(cnt, gen);

        dec = decb;
        hin = hout;
        cin = cout;
    }
}

__global__ void mask_out(const unsigned char* __restrict__ mask, float* __restrict__ out)
{
    int t = blockIdx.x * 256 + threadIdx.x;
    if (t < B * NN)
        out[(long)B * NN * NN + (long)B * NN + t] = mask[t] ? 1.f : 0.f;
}

// ---------------------------------------------------------------------------
extern "C" void kernel_launch(void* const* d_in, const int* in_sizes, int n_in,
                              void* d_out, int out_size, void* d_ws, size_t ws_size,
                              hipStream_t stream)
{
    const float* decoder_input = (const float*)d_in[0];
    const float* embedded     = (const float*)d_in[1];
    const float* h0           = (const float*)d_in[2];
    const float* c0           = (const float*)d_in[3];
    const float* context      = (const float*)d_in[4];
    const float* embed_cou    = (const float*)d_in[5];
    const float* D            = (const float*)d_in[6];
    const float* W_ih         = (const float*)d_in[7];
    const float* W_hh         = (const float*)d_in[8];
    const float* b_ih         = (const float*)d_in[9];
    const float* b_hh         = (const float*)d_in[10];
    const float* W_merge      = (const float*)d_in[11];
    const float* b_merge      = (const float*)d_in[12];
    const float* Wq_p         = (const float*)d_in[13];
    const float* bq_p         = (const float*)d_in[14];
    const float* Wr_p         = (const float*)d_in[15];
    const float* br_p         = (const float*)d_in[16];
    const float* v_p          = (const float*)d_in[17];
    const float* Wq_g         = (const float*)d_in[18];
    const float* bq_g         = (const float*)d_in[19];
    const float* Wr_g         = (const float*)d_in[20];
    const float* br_g         = (const float*)d_in[21];
    const float* v_g          = (const float*)d_in[22];
    const unsigned char* vreach = (const unsigned char*)d_in[23];
    const int* start_idx      = (const int*)d_in[24];
    const int* kminp          = (const int*)d_in[25];

    float* ws = (float*)d_ws;
    size_t o = 0;
    float* eg     = ws + o; o += (size_t)B * NN * H;   // [NN][B][H]
    float* ep     = ws + o; o += (size_t)B * NN * H;   // [NN][B][H]
    float* Fbuf   = ws + o; o += (size_t)B * NN * H;   // [NN][B][H]
    float* hb0    = ws + o; o += (size_t)B * H;
    float* hb1    = ws + o; o += (size_t)B * H;
    float* cb0    = ws + o; o += (size_t)B * H;
    float* cb1    = ws + o; o += (size_t)B * H;
    float* qbuf   = ws + o; o += (size_t)B * H;
    float* decb   = ws + o; o += (size_t)B * H;
    float* qc     = ws + o; o += (size_t)B * H;
    float* W1c    = ws + o; o += (size_t)H * H;
    float* W2c    = ws + o; o += (size_t)H * 32;
    float* bc     = ws + o; o += (size_t)H;
    float* WFc    = ws + o; o += (size_t)H * H;
    float* bFc    = ws + o; o += (size_t)H;
    float* Wih2   = ws + o; o += (size_t)G4 * H;
    float* Whh2   = ws + o; o += (size_t)G4 * H;
    float* bg     = ws + o; o += (size_t)G4;
    unsigned char* maskb = (unsigned char*)(ws + o);
    unsigned char* knnb  = maskb + (size_t)B * NN;
    int* idxs = (int*)(knnb + (size_t)B * NN + 64);
    unsigned* bar = (unsigned*)(idxs + B + 16);

    float* out = (float*)d_out;

    init_state<<<dim3((B * NN + 255) / 256), dim3(256), 0, stream>>>(
        vreach, start_idx, maskb, knnb, idxs, bar);

    prep_reorder<<<dim3(G4), dim3(256), 0, stream>>>(W_ih, W_hh, b_ih, b_hh,
                                                     Wih2, Whh2, bg);
    prep_compose1<<<dim3(H), dim3(256), 0, stream>>>(Wq_g, W_merge, W1c);
    prep_compose2<<<dim3(H), dim3(64), 0, stream>>>(Wq_g, W_merge, b_merge, bq_g,
                                                    W2c, bc);
    prep_qc<<<dim3(B), dim3(256), 0, stream>>>(embed_cou, W2c, bc, qc);
    prep_composeF<<<dim3(H), dim3(256), 0, stream>>>(Wq_p, Wr_g, br_g, WFc, bFc);

    gemm_big<<<dim3(6, (B * NN) / 128), dim3(256), 0, stream>>>(
        context, Wr_g, Wr_p, WFc, br_g, br_p, bFc, eg, ep, Fbuf);

    decode_loop<<<dim3(NBLK), dim3(512), 0, stream>>>(
        decoder_input, embedded, h0, c0, Wih2, Whh2, bg, W1c, qc,
        eg, ep, Fbuf, v_g, v_p, bq_p, D, kminp,
        maskb, knnb, out, idxs, hb0, hb1, cb0, cb1, qbuf, decb, bar);

    mask_out<<<dim3((B * NN + 255) / 256), dim3(256), 0, stream>>>(maskb, out);
}

// Round 11
// 2995.678 us; speedup vs baseline: 3.3526x; 3.3526x over previous
//
#include <hip/hip_runtime.h>
#include <hip/hip_bf16.h>
#include <math.h>

#define B 2048
#define NN 30
#define H 256
#define EDIM 256
#define G4 1024  // 4*H

__device__ __forceinline__ float fsig(float x) {
    return __fdividef(1.f, 1.f + __expf(-x));
}
__device__ __forceinline__ float ftanh(float x) {
    return 1.f - __fdividef(2.f, __expf(2.f * x) + 1.f);
}

// ---------------------------------------------------------------------------
// Big precompute GEMM: A [M][256] x three 256x256 W^T -> C0/C1/C2 [M][256].
// 128x128 tile, 8x8/thread, single-buffered, XCD swizzle. (R7-proven: 294us)
// ---------------------------------------------------------------------------
__global__ __launch_bounds__(256)
void gemm_big(const float* __restrict__ A,
              const float* __restrict__ W0, const float* __restrict__ W1,
              const float* __restrict__ W2,
              const float* __restrict__ b0, const float* __restrict__ b1,
              const float* __restrict__ b2,
              float* __restrict__ C0, float* __restrict__ C1,
              float* __restrict__ C2)
{
    __shared__ __align__(16) float As[16][128];
    __shared__ __align__(16) float Ws[16][128];
    int tid = threadIdx.x;
    int tx = tid & 15, ty = (tid >> 4) & 15;

    int lin = blockIdx.y * 6 + blockIdx.x;
    int v = (lin & 7) * 360 + (lin >> 3);
    int m0 = (v / 6) << 7;
    int nblk = v % 6;
    int part = nblk >> 1;
    int nin = (nblk & 1) << 7;
    const float* W    = part == 0 ? W0 : part == 1 ? W1 : W2;
    const float* bias = part == 0 ? b0 : part == 1 ? b1 : b2;
    float* C          = part == 0 ? C0 : part == 1 ? C1 : C2;

    int lr = tid >> 1;
    int lk8 = (tid & 1) << 3;
    const float* arow = A + (long)(m0 + lr) * 256 + lk8;
    const float* wrow = W + (long)(nin + lr) * 256 + lk8;
    float4 a0 = *(const float4*)(arow);
    float4 a1 = *(const float4*)(arow + 4);
    float4 w0 = *(const float4*)(wrow);
    float4 w1 = *(const float4*)(wrow + 4);
    float acc[8][8] = {};

    for (int k0 = 0; k0 < 256; k0 += 16) {
        As[lk8 + 0][lr] = a0.x; As[lk8 + 1][lr] = a0.y;
        As[lk8 + 2][lr] = a0.z; As[lk8 + 3][lr] = a0.w;
        As[lk8 + 4][lr] = a1.x; As[lk8 + 5][lr] = a1.y;
        As[lk8 + 6][lr] = a1.z; As[lk8 + 7][lr] = a1.w;
        Ws[lk8 + 0][lr] = w0.x; Ws[lk8 + 1][lr] = w0.y;
        Ws[lk8 + 2][lr] = w0.z; Ws[lk8 + 3][lr] = w0.w;
        Ws[lk8 + 4][lr] = w1.x; Ws[lk8 + 5][lr] = w1.y;
        Ws[lk8 + 6][lr] = w1.z; Ws[lk8 + 7][lr] = w1.w;
        __syncthreads();
        if (k0 + 16 < 256) {
            a0 = *(const float4*)(arow + k0 + 16);
            a1 = *(const float4*)(arow + k0 + 20);
            w0 = *(const float4*)(wrow + k0 + 16);
            w1 = *(const float4*)(wrow + k0 + 20);
        }
        #pragma unroll
        for (int k = 0; k < 16; ++k) {
            float4 af0 = *(const float4*)&As[k][ty << 2];
            float4 af1 = *(const float4*)&As[k][64 + (ty << 2)];
            float4 wf0 = *(const float4*)&Ws[k][tx << 2];
            float4 wf1 = *(const float4*)&Ws[k][64 + (tx << 2)];
            float av[8] = {af0.x, af0.y, af0.z, af0.w, af1.x, af1.y, af1.z, af1.w};
            float wv[8] = {wf0.x, wf0.y, wf0.z, wf0.w, wf1.x, wf1.y, wf1.z, wf1.w};
            #pragma unroll
            for (int i = 0; i < 8; ++i)
                #pragma unroll
                for (int j = 0; j < 8; ++j)
                    acc[i][j] = fmaf(av[i], wv[j], acc[i][j]);
        }
        __syncthreads();
    }

    float bj[8];
    #pragma unroll
    for (int j = 0; j < 8; ++j) {
        int cj = nin + ((j < 4) ? (tx << 2) + j : 64 + (tx << 2) + j - 4);
        bj[j] = bias[cj];
    }
    #pragma unroll
    for (int i = 0; i < 8; ++i) {
        int m = m0 + ((i < 4) ? (ty << 2) + i : 64 + (ty << 2) + i - 4);
        float* crow = C + (long)m * 256 + nin;
        float4 v0 = make_float4(acc[i][0] + bj[0], acc[i][1] + bj[1],
                                acc[i][2] + bj[2], acc[i][3] + bj[3]);
        float4 v1 = make_float4(acc[i][4] + bj[4], acc[i][5] + bj[5],
                                acc[i][6] + bj[6], acc[i][7] + bj[7]);
        *(float4*)&crow[(tx << 2)] = v0;
        *(float4*)&crow[64 + (tx << 2)] = v1;
    }
}

// ---------------------------------------------------------------------------
// Fused LSTM gates GEMM + activation (quad-interleaved weights), K=512,
// 64x64 tile, double-buffered, 512 blocks (R7-proven).
// ---------------------------------------------------------------------------
__global__ __launch_bounds__(256)
void gates_lstm(const float* __restrict__ A1, const float* __restrict__ A2,
                const float* __restrict__ W1, const float* __restrict__ W2,
                const float* __restrict__ bg, const float* __restrict__ cin,
                float* __restrict__ hout, float* __restrict__ cout)
{
    __shared__ __align__(16) float As[2][16][68];
    __shared__ __align__(16) float Ws[2][16][68];
    int tid = threadIdx.x;
    int tx = tid & 15, ty = tid >> 4;

    int lin = blockIdx.y * 16 + blockIdx.x;
    int v = (lin & 7) * 64 + (lin >> 3);
    int m0 = (v >> 4) << 6;
    int n0 = (v & 15) << 6;

    int lr = tid >> 2;
    int lk = (tid & 3) << 2;
    const float* arow0 = A1 + (long)(m0 + lr) * H;
    const float* arow1 = A2 + (long)(m0 + lr) * H;
    const float* wrow0 = W1 + (long)(n0 + lr) * H;
    const float* wrow1 = W2 + (long)(n0 + lr) * H;

    float4 av = *(const float4*)(arow0 + lk);
    float4 wv = *(const float4*)(wrow0 + lk);
    As[0][lk + 0][lr] = av.x; As[0][lk + 1][lr] = av.y;
    As[0][lk + 2][lr] = av.z; As[0][lk + 3][lr] = av.w;
    Ws[0][lk + 0][lr] = wv.x; Ws[0][lk + 1][lr] = wv.y;
    Ws[0][lk + 2][lr] = wv.z; Ws[0][lk + 3][lr] = wv.w;
    __syncthreads();

    float acc[4][4] = {};
    int p = 0;
    for (int kk = 0; kk < 32; ++kk) {
        float4 nav, nwv;
        bool more = kk < 31;
        if (more) {
            int nk = kk + 1;
            const float* ar = (nk & 16) ? arow1 : arow0;
            const float* wr = (nk & 16) ? wrow1 : wrow0;
            int off = (nk & 15) << 4;
            nav = *(const float4*)(ar + off + lk);
            nwv = *(const float4*)(wr + off + lk);
        }
        #pragma unroll
        for (int k = 0; k < 16; ++k) {
            float4 a4 = *(const float4*)&As[p][k][ty << 2];
            float4 b4 = *(const float4*)&Ws[p][k][tx << 2];
            float a[4] = {a4.x, a4.y, a4.z, a4.w};
            float w[4] = {b4.x, b4.y, b4.z, b4.w};
            #pragma unroll
            for (int i = 0; i < 4; ++i)
                #pragma unroll
                for (int j = 0; j < 4; ++j)
                    acc[i][j] = fmaf(a[i], w[j], acc[i][j]);
        }
        if (more) {
            int q = p ^ 1;
            As[q][lk + 0][lr] = nav.x; As[q][lk + 1][lr] = nav.y;
            As[q][lk + 2][lr] = nav.z; As[q][lk + 3][lr] = nav.w;
            Ws[q][lk + 0][lr] = nwv.x; Ws[q][lk + 1][lr] = nwv.y;
            Ws[q][lk + 2][lr] = nwv.z; Ws[q][lk + 3][lr] = nwv.w;
        }
        __syncthreads();
        p ^= 1;
    }

    int nb = n0 + (tx << 2);
    float b0 = bg[nb + 0], b1 = bg[nb + 1], b2 = bg[nb + 2], b3 = bg[nb + 3];
    int hq = (n0 >> 2) + tx;
    #pragma unroll
    for (int i = 0; i < 4; ++i) {
        int m = m0 + (ty << 2) + i;
        float gi_ = acc[i][0] + b0;
        float gf_ = acc[i][1] + b1;
        float gg_ = acc[i][2] + b2;
        float go_ = acc[i][3] + b3;
        float cv = cin[(long)m * H + hq];
        float cn = fsig(gf_) * cv + fsig(gi_) * ftanh(gg_);
        float hn = fsig(go_) * ftanh(cn);
        cout[(long)m * H + hq] = cn;
        hout[(long)m * H + hq] = hn;
    }
}

// ---------------------------------------------------------------------------
// qg GEMM: qbuf[2048][256] = h @ W1c^T + qc.  32x64 tile -> 256 blocks.
// ---------------------------------------------------------------------------
__global__ __launch_bounds__(256)
void gemm_qg(const float* __restrict__ A, const float* __restrict__ W,
             const float* __restrict__ addend, float* __restrict__ C)
{
    __shared__ __align__(16) float As[2][16][36];
    __shared__ __align__(16) float Ws[2][16][68];
    int tid = threadIdx.x;
    int tx = tid & 15, ty = tid >> 4;

    int lin = blockIdx.y * 4 + blockIdx.x;
    int v = (lin & 7) * 32 + (lin >> 3);
    int m0 = (v >> 2) << 5;
    int n0 = (v & 3) << 6;

    int lrA = tid >> 3, lkA = (tid & 7) << 1;
    int lrW = tid >> 2, lkW = (tid & 3) << 2;
    const float* arow = A + (long)(m0 + lrA) * 256;
    const float* wrow = W + (long)(n0 + lrW) * 256;

    float2 av = *(const float2*)(arow + lkA);
    float4 wv = *(const float4*)(wrow + lkW);
    As[0][lkA + 0][lrA] = av.x; As[0][lkA + 1][lrA] = av.y;
    Ws[0][lkW + 0][lrW] = wv.x; Ws[0][lkW + 1][lrW] = wv.y;
    Ws[0][lkW + 2][lrW] = wv.z; Ws[0][lkW + 3][lrW] = wv.w;
    __syncthreads();

    float acc[2][4] = {};
    int p = 0;
    for (int k0 = 0; k0 < 256; k0 += 16) {
        float2 nav; float4 nwv;
        bool more = (k0 + 16) < 256;
        if (more) {
            nav = *(const float2*)(arow + k0 + 16 + lkA);
            nwv = *(const float4*)(wrow + k0 + 16 + lkW);
        }
        #pragma unroll
        for (int k = 0; k < 16; ++k) {
            float2 a2 = *(const float2*)&As[p][k][ty << 1];
            float4 b4 = *(const float4*)&Ws[p][k][tx << 2];
            acc[0][0] = fmaf(a2.x, b4.x, acc[0][0]);
            acc[0][1] = fmaf(a2.x, b4.y, acc[0][1]);
            acc[0][2] = fmaf(a2.x, b4.z, acc[0][2]);
            acc[0][3] = fmaf(a2.x, b4.w, acc[0][3]);
            acc[1][0] = fmaf(a2.y, b4.x, acc[1][0]);
            acc[1][1] = fmaf(a2.y, b4.y, acc[1][1]);
            acc[1][2] = fmaf(a2.y, b4.z, acc[1][2]);
            acc[1][3] = fmaf(a2.y, b4.w, acc[1][3]);
        }
        if (more) {
            int q = p ^ 1;
            As[q][lkA + 0][lrA] = nav.x; As[q][lkA + 1][lrA] = nav.y;
            Ws[q][lkW + 0][lrW] = nwv.x; Ws[q][lkW + 1][lrW] = nwv.y;
            Ws[q][lkW + 2][lrW] = nwv.z; Ws[q][lkW + 3][lrW] = nwv.w;
        }
        __syncthreads();
        p ^= 1;
    }

    #pragma unroll
    for (int i = 0; i < 2; ++i) {
        int m = m0 + (ty << 1) + i;
        const float* ad = &addend[(long)m * 256 + n0 + (tx << 2)];
        float4 adv = *(const float4*)ad;
        float4 o = make_float4(acc[i][0] + adv.x, acc[i][1] + adv.y,
                               acc[i][2] + adv.z, acc[i][3] + adv.w);
        *(float4*)&C[(long)m * 256 + n0 + (tx << 2)] = o;
    }
}

__global__ void init_state(const unsigned char* __restrict__ vr, const int* __restrict__ start,
                           unsigned char* __restrict__ mask, unsigned char* __restrict__ knn,
                           int* __restrict__ idxs)
{
    int t = blockIdx.x * 256 + threadIdx.x;
    if (t < B * NN) { mask[t] = vr[t] ? 1 : 0; knn[t] = 0; }
    if (t < B) idxs[t] = start[t];
}

// --------------------------- one-time prep kernels -------------------------
__global__ void prep_reorder(const float* __restrict__ Wih, const float* __restrict__ Whh,
                             const float* __restrict__ bih, const float* __restrict__ bhh,
                             float* __restrict__ Wih2, float* __restrict__ Whh2,
                             float* __restrict__ bg)
{
    int n = blockIdx.x, k = threadIdx.x;
    int src = ((n & 3) << 8) + (n >> 2);
    Wih2[(long)n * H + k] = Wih[(long)src * H + k];
    Whh2[(long)n * H + k] = Whh[(long)src * H + k];
    if (k == 0) bg[n] = bih[src] + bhh[src];
}

__global__ void prep_compose1(const float* __restrict__ Wqg, const float* __restrict__ Wm,
                              float* __restrict__ W1c)
{
    int h = blockIdx.x, k = threadIdx.x;
    float a = 0.f;
    for (int j = 0; j < H; ++j) a = fmaf(Wqg[(long)h * H + j], Wm[(long)j * 288 + k], a);
    W1c[(long)h * H + k] = a;
}

__global__ void prep_compose2(const float* __restrict__ Wqg, const float* __restrict__ Wm,
                              const float* __restrict__ bm, const float* __restrict__ bqg,
                              float* __restrict__ W2c, float* __restrict__ bc)
{
    int h = blockIdx.x, w = threadIdx.x;
    if (w < 32) {
        float a = 0.f;
        for (int j = 0; j < H; ++j) a = fmaf(Wqg[(long)h * H + j], Wm[(long)j * 288 + 256 + w], a);
        W2c[h * 32 + w] = a;
    } else if (w == 32) {
        float a = 0.f;
        for (int j = 0; j < H; ++j) a = fmaf(Wqg[(long)h * H + j], bm[j], a);
        bc[h] = a + bqg[h];
    }
}

__global__ __launch_bounds__(256)
void prep_qc(const float* __restrict__ cou, const float* __restrict__ W2c,
             const float* __restrict__ bc, float* __restrict__ qc)
{
    __shared__ float sWT[32 * 256];
    __shared__ float sb[256];
    int b = blockIdx.x, h = threadIdx.x;
    for (int i = h; i < 32 * 256; i += 256) {
        int hh = i >> 5, ww = i & 31;
        sWT[ww * 256 + hh] = W2c[i];
    }
    sb[h] = bc[h];
    __syncthreads();
    const float* cr = cou + (long)b * 32;
    float a = sb[h];
    for (int w = 0; w < 32; ++w) a = fmaf(cr[w], sWT[w * 256 + h], a);
    qc[(long)b * H + h] = a;
}

__global__ void prep_composeF(const float* __restrict__ Wqp, const float* __restrict__ Wrg,
                              const float* __restrict__ brg, float* __restrict__ WFc,
                              float* __restrict__ bFc)
{
    int f = blockIdx.x, k = threadIdx.x;
    float a = 0.f;
    for (int j = 0; j < H; ++j) a = fmaf(Wqp[(long)f * H + j], Wrg[(long)j * H + k], a);
    WFc[(long)f * H + k] = a;
    if (k == 0) {
        float s = 0.f;
        for (int j = 0; j < H; ++j) s = fmaf(Wqp[(long)f * H + j], brg[j], s);
        bFc[f] = s;
    }
}

// ---------------------------------------------------------------------------
// Mega attention (512 thr): mask/knn -> u_g -> softmax -> q_p via F ->
// u_p -> log_softmax/argmax/outputs -> gather dec. e layout: [NN][B][H].
// Masked-n SKIP: phases 1/4 skip n with sFull[n] (their sU is never read);
// phase 3 skips sP==0 terms (exact 0 contribution). Wave-uniform branches;
// zero change to any consumed value -> decisions identical to R7.
// ---------------------------------------------------------------------------
__global__ __launch_bounds__(512)
void mega_attn2(const float* __restrict__ eg, const float* __restrict__ ep,
                const float* __restrict__ F, const float* __restrict__ qg,
                const float* __restrict__ vg, const float* __restrict__ vp,
                const float* __restrict__ bqp,
                const float* __restrict__ D, const int* __restrict__ kminp,
                unsigned char* __restrict__ mask, unsigned char* __restrict__ knn,
                const float* __restrict__ emb,
                float* __restrict__ out, int step,
                int* __restrict__ idxs, float* __restrict__ decbuf)
{
    int b = blockIdx.x, tid = threadIdx.x;
    int wv = tid >> 6, lane = tid & 63;
    __shared__ float sU[32], sP[32];
    __shared__ float sQp[H];
    __shared__ float sPar[2][H];
    __shared__ unsigned char sFull[32];
    __shared__ int sSel;

    float4 q4  = ((const float4*)(qg + (long)b * H))[lane];
    float4 vg4 = ((const float4*)vg)[lane];
    float4 vp4 = ((const float4*)vp)[lane];

    if (tid < 64) {
        bool in = lane < NN;
        int idx = idxs[b];
        int kmin = *kminp;
        unsigned char m = in ? mask[b * NN + lane] : (unsigned char)1;
        float dv = in ? D[((long)b * NN + idx) * NN + lane] : 0.f;
        unsigned long long unm = __ballot(in && !m);
        int cnt = __popcll(unm);
        bool valid = cnt > kmin;
        float bw = (in && !m) ? dv : (in ? 0.f : -1.f);
        int bi = in ? lane : 1000;
        #pragma unroll
        for (int off = 32; off; off >>= 1) {
            float ow = __shfl_down(bw, off, 64);
            int oi = __shfl_down(bi, off, 64);
            if (ow > bw || (ow == bw && oi < bi)) { bw = ow; bi = oi; }
        }
        int far = __shfl(bi, 0, 64);
        unsigned char mnew = (in && lane == idx) ? 1 : m;
        #pragma unroll
        for (int rep = 0; rep < 2; ++rep) {
            bool allm = (__ballot(in && !mnew) == 0ull);
            if (allm && lane == NN - 1) mnew = 0;
        }
        unsigned char kn = in ? knn[b * NN + lane] : 0;
        if (in) {
            sFull[lane] = (mnew | kn) ? 1 : 0;
            mask[b * NN + lane] = mnew;
            knn[b * NN + lane] = (lane == far && valid) ? 1 : 0;
        }
    }
    __syncthreads();

    // u_g: skip masked n (sU[n] unread when masked)
    for (int n = wv; n < NN; n += 8) {
        if (sFull[n]) continue;
        float4 e4 = ((const float4*)(eg + ((long)n * B + b) * H))[lane];
        float s = vg4.x * ftanh(q4.x + e4.x);
        s = fmaf(vg4.y, ftanh(q4.y + e4.y), s);
        s = fmaf(vg4.z, ftanh(q4.z + e4.z), s);
        s = fmaf(vg4.w, ftanh(q4.w + e4.w), s);
        #pragma unroll
        for (int off = 32; off; off >>= 1) s += __shfl_down(s, off, 64);
        if (lane == 0) sU[n] = s;
    }
    __syncthreads();

    if (tid < 64) {
        bool in = tid < NN;
        bool f = in ? (sFull[tid] != 0) : true;
        float u = (in && !f) ? sU[tid] : -INFINITY;
        float mx = u;
        #pragma unroll
        for (int off = 32; off; off >>= 1) mx = fmaxf(mx, __shfl_down(mx, off, 64));
        mx = __shfl(mx, 0, 64);
        float p = (in && !f) ? __expf(u - mx) : 0.f;
        float sum = p;
        #pragma unroll
        for (int off = 32; off; off >>= 1) sum += __shfl_down(sum, off, 64);
        sum = __shfl(sum, 0, 64);
        if (in) sP[tid] = p / sum;
    }
    __syncthreads();

    // q_p = bqp + sum_n p_n F[n,b,:]  (n split; skip exact-zero p)
    {
        int half = tid >> 8, hh = tid & 255;
        float a = 0.f;
        #pragma unroll
        for (int n = 0; n < 15; ++n) {
            int nn = half * 15 + n;
            float pn = sP[nn];
            if (pn != 0.f)
                a = fmaf(pn, F[((long)nn * B + b) * H + hh], a);
        }
        sPar[half][hh] = a;
    }
    __syncthreads();
    if (tid < 256) sQp[tid] = bqp[tid] + sPar[0][tid] + sPar[1][tid];
    __syncthreads();

    // u_p: skip masked n
    float4 qp4 = ((const float4*)sQp)[lane];
    for (int n = wv; n < NN; n += 8) {
        if (sFull[n]) continue;
        float4 e4 = ((const float4*)(ep + ((long)n * B + b) * H))[lane];
        float s = vp4.x * ftanh(qp4.x + e4.x);
        s = fmaf(vp4.y, ftanh(qp4.y + e4.y), s);
        s = fmaf(vp4.z, ftanh(qp4.z + e4.z), s);
        s = fmaf(vp4.w, ftanh(qp4.w + e4.w), s);
        #pragma unroll
        for (int off = 32; off; off >>= 1) s += __shfl_down(s, off, 64);
        if (lane == 0) sU[n] = 10.f * ftanh(s);
    }
    __syncthreads();

    if (tid < 64) {
        bool in = tid < NN;
        bool f = in ? (sFull[tid] != 0) : true;
        float l = (in && !f) ? sU[tid] : -INFINITY;
        float mx = l; int bi = in ? tid : 1000;
        #pragma unroll
        for (int off = 32; off; off >>= 1) {
            float om = __shfl_down(mx, off, 64);
            int oi = __shfl_down(bi, off, 64);
            if (om > mx || (om == mx && oi < bi)) { mx = om; bi = oi; }
        }
        mx = __shfl(mx, 0, 64);
        bi = __shfl(bi, 0, 64);
        float pe = (in && !f) ? __expf(l - mx) : 0.f;
        float sum = pe;
        #pragma unroll
        for (int off = 32; off; off >>= 1) sum += __shfl_down(sum, off, 64);
        sum = __shfl(sum, 0, 64);
        float lse = mx + __logf(sum);
        if (tid == 0) {
            idxs[b] = bi;
            out[(long)B * NN * NN + (long)b * NN + step] = (float)bi;
            sSel = bi;
        }
        if (in)
            out[(long)b * NN * NN + (long)step * NN + tid] =
                f ? -1e30f : (l - lse);
    }
    __syncthreads();

    if (tid < 256) {
        int sel = sSel;
        decbuf[(long)b * H + tid] = emb[((long)sel * B + b) * EDIM + tid];
    }
}

__global__ void mask_out(const unsigned char* __restrict__ mask, float* __restrict__ out)
{
    int t = blockIdx.x * 256 + threadIdx.x;
    if (t < B * NN)
        out[(long)B * NN * NN + (long)B * NN + t] = mask[t] ? 1.f : 0.f;
}

// ---------------------------------------------------------------------------
extern "C" void kernel_launch(void* const* d_in, const int* in_sizes, int n_in,
                              void* d_out, int out_size, void* d_ws, size_t ws_size,
                              hipStream_t stream)
{
    const float* decoder_input = (const float*)d_in[0];
    const float* embedded     = (const float*)d_in[1];
    const float* h0           = (const float*)d_in[2];
    const float* c0           = (const float*)d_in[3];
    const float* context      = (const float*)d_in[4];
    const float* embed_cou    = (const float*)d_in[5];
    const float* D            = (const float*)d_in[6];
    const float* W_ih         = (const float*)d_in[7];
    const float* W_hh         = (const float*)d_in[8];
    const float* b_ih         = (const float*)d_in[9];
    const float* b_hh         = (const float*)d_in[10];
    const float* W_merge      = (const float*)d_in[11];
    const float* b_merge      = (const float*)d_in[12];
    const float* Wq_p         = (const float*)d_in[13];
    const float* bq_p         = (const float*)d_in[14];
    const float* Wr_p         = (const float*)d_in[15];
    const float* br_p         = (const float*)d_in[16];
    const float* v_p          = (const float*)d_in[17];
    const float* Wq_g         = (const float*)d_in[18];
    const float* bq_g         = (const float*)d_in[19];
    const float* Wr_g         = (const float*)d_in[20];
    const float* br_g         = (const float*)d_in[21];
    const float* v_g          = (const float*)d_in[22];
    const unsigned char* vreach = (const unsigned char*)d_in[23];
    const int* start_idx      = (const int*)d_in[24];
    const int* kminp          = (const int*)d_in[25];

    float* ws = (float*)d_ws;
    size_t o = 0;
    float* eg     = ws + o; o += (size_t)B * NN * H;   // [NN][B][H]
    float* ep     = ws + o; o += (size_t)B * NN * H;   // [NN][B][H]
    float* Fbuf   = ws + o; o += (size_t)B * NN * H;   // [NN][B][H]
    float* hb0    = ws + o; o += (size_t)B * H;
    float* hb1    = ws + o; o += (size_t)B * H;
    float* cb0    = ws + o; o += (size_t)B * H;
    float* cb1    = ws + o; o += (size_t)B * H;
    float* qbuf   = ws + o; o += (size_t)B * H;
    float* decb   = ws + o; o += (size_t)B * H;
    float* qc     = ws + o; o += (size_t)B * H;
    float* W1c    = ws + o; o += (size_t)H * H;
    float* W2c    = ws + o; o += (size_t)H * 32;
    float* bc     = ws + o; o += (size_t)H;
    float* WFc    = ws + o; o += (size_t)H * H;
    float* bFc    = ws + o; o += (size_t)H;
    float* Wih2   = ws + o; o += (size_t)G4 * H;
    float* Whh2   = ws + o; o += (size_t)G4 * H;
    float* bg     = ws + o; o += (size_t)G4;
    unsigned char* maskb = (unsigned char*)(ws + o);
    unsigned char* knnb  = maskb + (size_t)B * NN;
    int* idxs = (int*)(knnb + (size_t)B * NN + 64);

    float* out = (float*)d_out;

    init_state<<<dim3((B * NN + 255) / 256), dim3(256), 0, stream>>>(
        vreach, start_idx, maskb, knnb, idxs);

    prep_reorder<<<dim3(G4), dim3(256), 0, stream>>>(W_ih, W_hh, b_ih, b_hh,
                                                     Wih2, Whh2, bg);
    prep_compose1<<<dim3(H), dim3(256), 0, stream>>>(Wq_g, W_merge, W1c);
    prep_compose2<<<dim3(H), dim3(64), 0, stream>>>(Wq_g, W_merge, b_merge, bq_g,
                                                    W2c, bc);
    prep_qc<<<dim3(B), dim3(256), 0, stream>>>(embed_cou, W2c, bc, qc);
    prep_composeF<<<dim3(H), dim3(256), 0, stream>>>(Wq_p, Wr_g, br_g, WFc, bFc);

    gemm_big<<<dim3(6, (B * NN) / 128), dim3(256), 0, stream>>>(
        context, Wr_g, Wr_p, WFc, br_g, br_p, bFc, eg, ep, Fbuf);

    const float* dec = decoder_input;
    const float* hin = h0;
    const float* cin = c0;

    for (int step = 0; step < NN; ++step) {
        int p = step & 1;
        float* hout = p ? hb1 : hb0;
        float* cout = p ? cb1 : cb0;

        gates_lstm<<<dim3(16, B / 64), dim3(256), 0, stream>>>(
            dec, hin, Wih2, Whh2, bg, cin, hout, cout);

        gemm_qg<<<dim3(4, B / 32), dim3(256), 0, stream>>>(
            hout, W1c, qc, qbuf);

        mega_attn2<<<dim3(B), dim3(512), 0, stream>>>(
            eg, ep, Fbuf, qbuf, v_g, v_p, bq_p, D, kminp,
            maskb, knnb, embedded, out, step, idxs, decb);

        dec = decb; hin = hout; cin = cout;
    }

    mask_out<<<dim3((B * NN + 255) / 256), dim3(256), 0, stream>>>(maskb, out);
}